// Round 5
// baseline (267.101 us; speedup 1.0000x reference)
//
#include <hip/hip_runtime.h>

#define N_TOK 576          // 24*24 patches per image
#define HP    24
#define PS    16
#define IMG   384
#define ATTN_SCALE 0.35355339059327373f   // 8^-0.5
#define NBLK  576          // grid size; must match launch

// Hand-rolled grid barrier. ctl = {cnt, flag}, both zeroed by host memset.
// Arrive: device-scope release + LLC fetch_add. Release: flag store.
// Spin: RELAXED agent loads (LLC reads, no repeated cache invalidation),
// then one acquire fence. Requires all NBLK blocks co-resident:
// 576 blocks / 256 CU -> 3 blocks/CU needed; 256 thr + ~6.3KB LDS +
// __launch_bounds__(256,3) guarantee >= 4 resident. [G16-safe: no
// dispatch-order assumption — all blocks participate symmetrically.]
__device__ __forceinline__ void gbar(unsigned* cnt, unsigned* flag)
{
    __syncthreads();
    if (threadIdx.x == 0) {
        __threadfence();   // release: writeback this XCD's dirty lines
        const unsigned old = __hip_atomic_fetch_add(
            cnt, 1u, __ATOMIC_ACQ_REL, __HIP_MEMORY_SCOPE_AGENT);
        if (old == NBLK - 1u) {
            __hip_atomic_store(flag, 1u, __ATOMIC_RELEASE,
                               __HIP_MEMORY_SCOPE_AGENT);
        } else {
            while (!__hip_atomic_load(flag, __ATOMIC_RELAXED,
                                      __HIP_MEMORY_SCOPE_AGENT))
                __builtin_amdgcn_s_sleep(4);
        }
        __threadfence();   // acquire: invalidate L1/L2 before cross-block reads
    }
    __syncthreads();
}

// One fused kernel: 576 blocks x 256 threads. Block handles tokens/patches
// {2*blk, 2*blk+1} in every phase (waves 0,1 active in phases 1-3).
// Only k1,v1,k2,v2 cross blocks (q stays in registers, sigmas in LDS).
__global__ __launch_bounds__(256, 3) void k_all(
    const float* __restrict__ x,
    const float* __restrict__ Wq, const float* __restrict__ bq,
    const float* __restrict__ Wk, const float* __restrict__ bk,
    const float* __restrict__ Wv, const float* __restrict__ bv,
    const float* __restrict__ Wsq, const float* __restrict__ bsq,
    const float* __restrict__ Wsk, const float* __restrict__ bsk,
    const float* __restrict__ Wsv, const float* __restrict__ bsv,
    const float* __restrict__ ln_g, const float* __restrict__ ln_b,
    const float* __restrict__ Wp,   const float* __restrict__ bp,
    float* __restrict__ k1, float* __restrict__ v1,
    float* __restrict__ k2, float* __restrict__ v2,
    unsigned* __restrict__ ctl,     // [0,1]=bar1 [2,3]=bar2 [4,5]=bar3 [6]=smax
    float* __restrict__ out)
{
    __shared__ float tile[32*40];      // bilateral tile, stride 40
    __shared__ float spt[17*17];       // spatial weight table
    __shared__ float s_sig[2][3];
    __shared__ int   s_half;

    const int t = threadIdx.x, lane = t & 63, w = t >> 6;
    const int blk = blockIdx.x;

    // ---------------- Phase 1: patchify + QKV1 (waves 0,1) ----------------
    float qv[8];                       // q1 row, carried in registers
    if (w < 2) {
        const int p  = blk*2 + w;      // global token/patch id, 0..1151
        const int b  = p / N_TOK, n = p % N_TOK;
        const int py = n / HP, px = n % HP;
        const int iy = lane >> 2, ix0 = (lane & 3) * 4;
        const float4 pv = *(const float4*)
            &x[b*IMG*IMG + (py*PS + iy)*IMG + px*PS + ix0];

        float acc[24];
#pragma unroll
        for (int j = 0; j < 24; ++j) acc[j] = 0.f;
#pragma unroll
        for (int j = 0; j < 4; ++j) {
            const int ft = 4*lane + j;            // feature index / W row
            const float pvj = ((const float*)&pv)[j];
#pragma unroll
            for (int h = 0; h < 8; ++h) {
                acc[h]      += pvj * Wq[ft*8 + h];
                acc[8 + h]  += pvj * Wk[ft*8 + h];
                acc[16 + h] += pvj * Wv[ft*8 + h];
            }
        }
#pragma unroll
        for (int off = 32; off; off >>= 1)
#pragma unroll
            for (int j = 0; j < 24; ++j) acc[j] += __shfl_xor(acc[j], off);

#pragma unroll
        for (int h = 0; h < 8; ++h) qv[h] = acc[h] + bq[h];
        if (lane >= 8 && lane < 16)
            k1[p*8 + (lane & 7)] = acc[8 + (lane & 7)]  + bk[lane & 7];
        if (lane >= 16 && lane < 24)
            v1[p*8 + (lane & 7)] = acc[16 + (lane & 7)] + bv[lane & 7];
    }
    gbar(ctl + 0, ctl + 1);

    // ---------------- Phase 2: attention 1 + QKV2 projection --------------
    float qv2[8];
    if (w < 2) {
        const int tok = blk*2 + w;
        const int b   = tok / N_TOK;
        const float* kbp = k1 + b*N_TOK*8;
        const float* vbp = v1 + b*N_TOK*8;

        float sc[9], mx = -1e30f;
#pragma unroll
        for (int ch = 0; ch < 9; ++ch) {
            const float4* kp = (const float4*)(kbp + (ch*64 + lane)*8);
            const float4 k0 = kp[0], k1r = kp[1];
            float d = qv[0]*k0.x + qv[1]*k0.y + qv[2]*k0.z + qv[3]*k0.w
                    + qv[4]*k1r.x + qv[5]*k1r.y + qv[6]*k1r.z + qv[7]*k1r.w;
            sc[ch] = d * ATTN_SCALE;
            mx = fmaxf(mx, sc[ch]);
        }
#pragma unroll
        for (int off = 32; off; off >>= 1) mx = fmaxf(mx, __shfl_xor(mx, off));

        float ssum = 0.f, o[8];
#pragma unroll
        for (int h = 0; h < 8; ++h) o[h] = 0.f;
#pragma unroll
        for (int ch = 0; ch < 9; ++ch) {
            const float pw = __expf(sc[ch] - mx);
            ssum += pw;
            const float4* vp = (const float4*)(vbp + (ch*64 + lane)*8);
            const float4 v0 = vp[0], v1r = vp[1];
            o[0] += pw*v0.x; o[1] += pw*v0.y; o[2] += pw*v0.z; o[3] += pw*v0.w;
            o[4] += pw*v1r.x; o[5] += pw*v1r.y; o[6] += pw*v1r.z; o[7] += pw*v1r.w;
        }
#pragma unroll
        for (int off = 32; off; off >>= 1) {
            ssum += __shfl_xor(ssum, off);
#pragma unroll
            for (int h = 0; h < 8; ++h) o[h] += __shfl_xor(o[h], off);
        }
        const float inv = 1.f/ssum;
        float f[8];
#pragma unroll
        for (int h = 0; h < 8; ++h) f[h] = o[h]*inv;

        float sproj = 0.f;
        if (lane < 24) {
            const int mat = lane >> 3, h = lane & 7;
            const float* Wm = (mat==0)?Wsq:(mat==1)?Wsk:Wsv;
            const float* bm = (mat==0)?bsq:(mat==1)?bsk:bsv;
            float s = bm[h];
#pragma unroll
            for (int j = 0; j < 8; ++j) s += f[j]*Wm[j*8 + h];
            sproj = s;
            if (mat == 1) k2[tok*8 + h] = s;
            if (mat == 2) v2[tok*8 + h] = s;
        }
#pragma unroll
        for (int h = 0; h < 8; ++h) qv2[h] = __shfl(sproj, h);  // q2 in regs
    }
    gbar(ctl + 2, ctl + 3);

    // ---------------- Phase 3: attention 2 + LN + BoundedSoftplus ---------
    if (w < 2) {
        const int tok = blk*2 + w;
        const int b   = tok / N_TOK;
        const float* kbp = k2 + b*N_TOK*8;
        const float* vbp = v2 + b*N_TOK*8;

        float sc[9], mx = -1e30f;
#pragma unroll
        for (int ch = 0; ch < 9; ++ch) {
            const float4* kp = (const float4*)(kbp + (ch*64 + lane)*8);
            const float4 k0 = kp[0], k1r = kp[1];
            float d = qv2[0]*k0.x + qv2[1]*k0.y + qv2[2]*k0.z + qv2[3]*k0.w
                    + qv2[4]*k1r.x + qv2[5]*k1r.y + qv2[6]*k1r.z + qv2[7]*k1r.w;
            sc[ch] = d * ATTN_SCALE;
            mx = fmaxf(mx, sc[ch]);
        }
#pragma unroll
        for (int off = 32; off; off >>= 1) mx = fmaxf(mx, __shfl_xor(mx, off));

        float ssum = 0.f, o[8];
#pragma unroll
        for (int h = 0; h < 8; ++h) o[h] = 0.f;
#pragma unroll
        for (int ch = 0; ch < 9; ++ch) {
            const float pw = __expf(sc[ch] - mx);
            ssum += pw;
            const float4* vp = (const float4*)(vbp + (ch*64 + lane)*8);
            const float4 v0 = vp[0], v1r = vp[1];
            o[0] += pw*v0.x; o[1] += pw*v0.y; o[2] += pw*v0.z; o[3] += pw*v0.w;
            o[4] += pw*v1r.x; o[5] += pw*v1r.y; o[6] += pw*v1r.z; o[7] += pw*v1r.w;
        }
#pragma unroll
        for (int off = 32; off; off >>= 1) {
            ssum += __shfl_xor(ssum, off);
#pragma unroll
            for (int h = 0; h < 8; ++h) o[h] += __shfl_xor(o[h], off);
        }

        if (lane == 0) {
            const float inv = 1.f/ssum;
            float f[8];
            float mu = 0.f;
#pragma unroll
            for (int h = 0; h < 8; ++h) { f[h] = o[h]*inv; mu += f[h]; }
            mu *= 0.125f;
            float var = 0.f;
#pragma unroll
            for (int h = 0; h < 8; ++h) { const float d = f[h]-mu; var += d*d; }
            var *= 0.125f;
            const float rinv = rsqrtf(var + 1e-5f);
            float on[8];
#pragma unroll
            for (int h = 0; h < 8; ++h)
                on[h] = (f[h]-mu)*rinv*ln_g[h] + ln_b[h];
            float sv[3];
#pragma unroll
            for (int c = 0; c < 3; ++c) {
                float z = bp[c];
#pragma unroll
                for (int j = 0; j < 8; ++j) z += on[j]*Wp[j*3 + c];
                const float sp = (z > 20.f) ? z : log1pf(__expf(z));
                sv[c] = fminf(sp, 6.0f) + 1e-6f;
                s_sig[w][c] = sv[c];       // sigmas never leave the block
            }
            atomicMax((int*)(ctl + 6), __float_as_int(fmaxf(sv[0], sv[1])));
        }
    }
    gbar(ctl + 4, ctl + 5);

    // ---------------- Phase 4: half + bilateral for patches 2blk,2blk+1 ---
    if (t == 0) {
        const int mi = __hip_atomic_load((const int*)(ctl + 6),
                                         __ATOMIC_RELAXED,
                                         __HIP_MEMORY_SCOPE_AGENT);
        const float m = __int_as_float(mi);
        int h = (int)ceilf(m + 1.0f);
        if (h < 1) h = 1;
        if (h > 8) h = 8;                  // sigma cap 6 -> h <= 8 always
        s_half = h;
    }
    __syncthreads();
    const int half  = s_half;
    const int k     = 2*half + 1;
    const int tilew = PS + 2*half;         // <= 32
    const int tx = t & 15, ty = t >> 4;

    for (int i = 0; i < 2; ++i) {
        const int p  = blk*2 + i;
        const int b  = p / N_TOK, n = p % N_TOK;
        const int py = n / HP, px = n % HP;
        const float sx = s_sig[i][0], sy = s_sig[i][1], sr = s_sig[i][2];
        const float* xb = x + b*IMG*IMG;

        for (int yy = ty; yy < tilew; yy += 16) {
            const int gy = py*PS + yy - half;
            for (int xx = tx; xx < tilew; xx += 16) {
                const int gx = px*PS + xx - half;
                float v = 0.f;             // zero padding, included in sums
                if ((unsigned)gy < IMG && (unsigned)gx < IMG)
                    v = xb[gy*IMG + gx];
                tile[yy*40 + xx] = v;
            }
        }
        {
            const float axc = -0.5f/(sx*sx);
            const float ayc = -0.5f/(sy*sy);
            for (int ii = t; ii < k*k; ii += 256) {
                const int dy = ii / k, dx = ii - dy*k;
                const float fy = (float)(dy - half), fx = (float)(dx - half);
                spt[ii] = __expf(ayc*fy*fy + axc*fx*fx);
            }
        }
        __syncthreads();

        const float c   = tile[(ty+half)*40 + (tx+half)];
        const float ar2 = -0.72134752044448170f/(sr*sr); // -0.5*log2(e)/sr^2
        float num = 0.f, den = 0.f;
        for (int dy = 0; dy < k; ++dy) {
            const float* row = &tile[(ty+dy)*40 + tx];
            const float* spr = &spt[dy*k];  // lane-uniform -> LDS broadcast
            for (int dx = 0; dx < k; ++dx) {
                const float pix = row[dx];
                const float d   = c - pix;
                const float wgt = spr[dx] * exp2f(ar2*d*d);
                den += wgt;
                num += wgt*pix;
            }
        }
        out[b*IMG*IMG + (py*PS + ty)*IMG + (px*PS + tx)] = num/(den + 1e-8f);
        __syncthreads();                   // WAR before next i reuses tile
    }
}

// ---------------- launch: tiny ctl memset + ONE kernel ---------------------
extern "C" void kernel_launch(void* const* d_in, const int* in_sizes, int n_in,
                              void* d_out, int out_size, void* d_ws, size_t ws_size,
                              hipStream_t stream)
{
    const float* x    = (const float*)d_in[0];
    const float* Wq   = (const float*)d_in[1];
    const float* bq   = (const float*)d_in[2];
    const float* Wk   = (const float*)d_in[3];
    const float* bk   = (const float*)d_in[4];
    const float* Wv   = (const float*)d_in[5];
    const float* bv   = (const float*)d_in[6];
    const float* Wsq  = (const float*)d_in[7];
    const float* bsq  = (const float*)d_in[8];
    const float* Wsk  = (const float*)d_in[9];
    const float* bsk  = (const float*)d_in[10];
    const float* Wsv  = (const float*)d_in[11];
    const float* bsv  = (const float*)d_in[12];
    const float* ln_g = (const float*)d_in[13];
    const float* ln_b = (const float*)d_in[14];
    const float* Wp   = (const float*)d_in[15];
    const float* bp   = (const float*)d_in[16];

    float* W  = (float*)d_ws;
    float* k1 = W;            // 2*576*8 = 9216 floats each
    float* v1 = W +  9216;
    float* k2 = W + 18432;
    float* v2 = W + 27648;
    unsigned* ctl = (unsigned*)(W + 36864);   // 7 words: 3x{cnt,flag} + smax

    hipMemsetAsync(ctl, 0, 32, stream);

    k_all<<<NBLK, 256, 0, stream>>>(x, Wq, bq, Wk, bk, Wv, bv,
                                    Wsq, bsq, Wsk, bsk, Wsv, bsv,
                                    ln_g, ln_b, Wp, bp,
                                    k1, v1, k2, v2, ctl, (float*)d_out);
}

// Round 6
// 161.020 us; speedup vs baseline: 1.6588x; 1.6588x over previous
//
#include <hip/hip_runtime.h>

#define N_TOK 576          // 24*24 patches per image
#define HP    24
#define PS    16
#define IMG   384
#define ATTN_SCALE 0.35355339059327373f   // 8^-0.5
#define NBLK  576          // grid size; must match launch
#define BAR_STRIDE 132     // per-barrier ctl: 8 grp ctrs @16-uint spacing,
                           // root @128, flag @129

// ---- uncached (agent-coherent) data path ----------------------------------
// All cross-block data moves via agent-scope relaxed atomics: these compile
// to sc-bit loads/stores that BYPASS L1/L2 and hit the device-coherent LLC.
// => no buffer_inv / buffer_wbl2 (the round-5 53us/barrier cost) ever needed.
__device__ __forceinline__ void stg_u32(float* p, float v) {
    union { float f; unsigned u; } c; c.f = v;
    __hip_atomic_store((unsigned*)p, c.u, __ATOMIC_RELAXED,
                       __HIP_MEMORY_SCOPE_AGENT);
}
__device__ __forceinline__ float2 ldg_f2(const float* p) {
    unsigned long long u = __hip_atomic_load(
        (const unsigned long long*)p, __ATOMIC_RELAXED,
        __HIP_MEMORY_SCOPE_AGENT);
    union { unsigned long long u; float2 f; } c; c.u = u; return c.f;
}
__device__ __forceinline__ void ldrow8(const float* p, float r[8]) {
    const float2 a = ldg_f2(p),   b = ldg_f2(p+2);
    const float2 c = ldg_f2(p+4), d = ldg_f2(p+6);
    r[0]=a.x; r[1]=a.y; r[2]=b.x; r[3]=b.y;
    r[4]=c.x; r[5]=c.y; r[6]=d.x; r[7]=d.y;
}

// ---- fence-free tree barrier ----------------------------------------------
// Visibility argument: __syncthreads() makes the compiler emit
// s_waitcnt vmcnt(0) per wave before s_barrier, and our sc1 data stores are
// acked by the LLC -> when thread 0 arrives, the block's data is LLC-visible.
// Readers use LLC-direct loads, so no acquire invalidate is needed either.
// Tree: 8 counters on separate 64B lines (72 arrivals each, parallel),
// then a root; spin is a relaxed LLC poll at s_sleep(8) (~0.2us) granularity.
// Deadlock-safe: 576 blocks, 256 thr, ~12.7KB LDS, __launch_bounds__(256,3)
// -> >=3 blocks/CU resident = 768 >= 576.
__device__ __forceinline__ void gbar(unsigned* base)
{
    __syncthreads();
    if (threadIdx.x == 0) {
        unsigned* grp  = base + (blockIdx.x & 7) * 16;
        unsigned* root = base + 128;
        unsigned* flag = base + 129;
        const unsigned old = __hip_atomic_fetch_add(
            grp, 1u, __ATOMIC_RELAXED, __HIP_MEMORY_SCOPE_AGENT);
        if (old == (NBLK/8) - 1u) {
            const unsigned r = __hip_atomic_fetch_add(
                root, 1u, __ATOMIC_RELAXED, __HIP_MEMORY_SCOPE_AGENT);
            if (r == 7u)
                __hip_atomic_store(flag, 1u, __ATOMIC_RELAXED,
                                   __HIP_MEMORY_SCOPE_AGENT);
        }
        while (!__hip_atomic_load(flag, __ATOMIC_RELAXED,
                                  __HIP_MEMORY_SCOPE_AGENT))
            __builtin_amdgcn_s_sleep(8);
    }
    __syncthreads();
}

// One fused kernel: 576 blocks x 256 threads. Block handles tokens/patches
// {2*blk, 2*blk+1}. Waves 0,1 run phases 1-3; waves 2,3 prefetch the
// worst-case (half=8) 32x32 bilateral tiles during phase 1.
__global__ __launch_bounds__(256, 3) void k_all(
    const float* __restrict__ x,
    const float* __restrict__ Wq, const float* __restrict__ bq,
    const float* __restrict__ Wk, const float* __restrict__ bk,
    const float* __restrict__ Wv, const float* __restrict__ bv,
    const float* __restrict__ Wsq, const float* __restrict__ bsq,
    const float* __restrict__ Wsk, const float* __restrict__ bsk,
    const float* __restrict__ Wsv, const float* __restrict__ bsv,
    const float* __restrict__ ln_g, const float* __restrict__ ln_b,
    const float* __restrict__ Wp,   const float* __restrict__ bp,
    float* __restrict__ k1, float* __restrict__ v1,
    float* __restrict__ k2, float* __restrict__ v2,
    unsigned* __restrict__ ctl,     // 3*BAR_STRIDE barrier words + smax
    float* __restrict__ out)
{
    __shared__ float tile[2][32*40];   // full half=8 windows, stride 40
    __shared__ float spt[2][17*17];    // per-patch spatial weight tables
    __shared__ float s_sig[2][3];
    __shared__ int   s_half;

    const int t = threadIdx.x, lane = t & 63, w = t >> 6;
    const int blk = blockIdx.x;
    unsigned* smax = ctl + 3*BAR_STRIDE;

    // ---------------- Phase 1: QKV1 (waves 0,1) + tile prefetch (2,3) -----
    float qv[8];                       // q1 row, carried in registers
    if (w < 2) {
        const int p  = blk*2 + w;      // token/patch id 0..1151
        const int b  = p / N_TOK, n = p % N_TOK;
        const int py = n / HP, px = n % HP;
        const int iy = lane >> 2, ix0 = (lane & 3) * 4;
        const float4 pv = *(const float4*)
            &x[b*IMG*IMG + (py*PS + iy)*IMG + px*PS + ix0];

        float acc[24];
#pragma unroll
        for (int j = 0; j < 24; ++j) acc[j] = 0.f;
#pragma unroll
        for (int j = 0; j < 4; ++j) {
            const int ft = 4*lane + j;
            const float pvj = ((const float*)&pv)[j];
#pragma unroll
            for (int h = 0; h < 8; ++h) {
                acc[h]      += pvj * Wq[ft*8 + h];
                acc[8 + h]  += pvj * Wk[ft*8 + h];
                acc[16 + h] += pvj * Wv[ft*8 + h];
            }
        }
#pragma unroll
        for (int off = 32; off; off >>= 1)
#pragma unroll
            for (int j = 0; j < 24; ++j) acc[j] += __shfl_xor(acc[j], off);

#pragma unroll
        for (int h = 0; h < 8; ++h) qv[h] = acc[h] + bq[h];
        if (lane >= 8 && lane < 16)
            stg_u32(&k1[p*8 + (lane & 7)], acc[8 + (lane & 7)]  + bk[lane & 7]);
        if (lane >= 16 && lane < 24)
            stg_u32(&v1[p*8 + (lane & 7)], acc[16 + (lane & 7)] + bv[lane & 7]);
    } else {
        // prefetch worst-case 32x32 window for patch i = w-2 (normal cached
        // loads: x is read-only input, no coherence concern)
        const int i  = w - 2;
        const int p  = blk*2 + i;
        const int b  = p / N_TOK, n = p % N_TOK;
        const int py = n / HP, px = n % HP;
        const float* xb = x + b*IMG*IMG;
        float* tl = tile[i];
#pragma unroll
        for (int j = 0; j < 16; ++j) {
            const int e  = j*64 + lane;          // 0..1023
            const int yy = e >> 5, xx = e & 31;
            const int gy = py*PS + yy - 8, gx = px*PS + xx - 8;
            float v = 0.f;                       // zero padding
            if ((unsigned)gy < IMG && (unsigned)gx < IMG)
                v = xb[gy*IMG + gx];
            tl[yy*40 + xx] = v;
        }
    }
    gbar(ctl + 0*BAR_STRIDE);

    // ---------------- Phase 2: attention 1 + QKV2 projection --------------
    float qv2[8];
    if (w < 2) {
        const int tok = blk*2 + w;
        const int b   = tok / N_TOK;
        const float* kbp = k1 + b*N_TOK*8;
        const float* vbp = v1 + b*N_TOK*8;

        float sc[9], mx = -1e30f;
#pragma unroll
        for (int ch = 0; ch < 9; ++ch) {
            float kr[8]; ldrow8(kbp + (ch*64 + lane)*8, kr);
            float d = 0.f;
#pragma unroll
            for (int h = 0; h < 8; ++h) d += qv[h]*kr[h];
            sc[ch] = d * ATTN_SCALE;
            mx = fmaxf(mx, sc[ch]);
        }
#pragma unroll
        for (int off = 32; off; off >>= 1) mx = fmaxf(mx, __shfl_xor(mx, off));

        float ssum = 0.f, o[8];
#pragma unroll
        for (int h = 0; h < 8; ++h) o[h] = 0.f;
#pragma unroll
        for (int ch = 0; ch < 9; ++ch) {
            float vr[8]; ldrow8(vbp + (ch*64 + lane)*8, vr);
            const float pw = __expf(sc[ch] - mx);
            ssum += pw;
#pragma unroll
            for (int h = 0; h < 8; ++h) o[h] += pw*vr[h];
        }
#pragma unroll
        for (int off = 32; off; off >>= 1) {
            ssum += __shfl_xor(ssum, off);
#pragma unroll
            for (int h = 0; h < 8; ++h) o[h] += __shfl_xor(o[h], off);
        }
        const float inv = 1.f/ssum;
        float f[8];
#pragma unroll
        for (int h = 0; h < 8; ++h) f[h] = o[h]*inv;

        float sproj = 0.f;
        if (lane < 24) {
            const int mat = lane >> 3, h = lane & 7;
            const float* Wm = (mat==0)?Wsq:(mat==1)?Wsk:Wsv;
            const float* bm = (mat==0)?bsq:(mat==1)?bsk:bsv;
            float s = bm[h];
#pragma unroll
            for (int j = 0; j < 8; ++j) s += f[j]*Wm[j*8 + h];
            sproj = s;
            if (mat == 1) stg_u32(&k2[tok*8 + h], s);
            if (mat == 2) stg_u32(&v2[tok*8 + h], s);
        }
#pragma unroll
        for (int h = 0; h < 8; ++h) qv2[h] = __shfl(sproj, h);  // q2 in regs
    }
    gbar(ctl + 1*BAR_STRIDE);

    // ---------------- Phase 3: attention 2 + LN + BoundedSoftplus ---------
    if (w < 2) {
        const int tok = blk*2 + w;
        const int b   = tok / N_TOK;
        const float* kbp = k2 + b*N_TOK*8;
        const float* vbp = v2 + b*N_TOK*8;

        float sc[9], mx = -1e30f;
#pragma unroll
        for (int ch = 0; ch < 9; ++ch) {
            float kr[8]; ldrow8(kbp + (ch*64 + lane)*8, kr);
            float d = 0.f;
#pragma unroll
            for (int h = 0; h < 8; ++h) d += qv2[h]*kr[h];
            sc[ch] = d * ATTN_SCALE;
            mx = fmaxf(mx, sc[ch]);
        }
#pragma unroll
        for (int off = 32; off; off >>= 1) mx = fmaxf(mx, __shfl_xor(mx, off));

        float ssum = 0.f, o[8];
#pragma unroll
        for (int h = 0; h < 8; ++h) o[h] = 0.f;
#pragma unroll
        for (int ch = 0; ch < 9; ++ch) {
            float vr[8]; ldrow8(vbp + (ch*64 + lane)*8, vr);
            const float pw = __expf(sc[ch] - mx);
            ssum += pw;
#pragma unroll
            for (int h = 0; h < 8; ++h) o[h] += pw*vr[h];
        }
#pragma unroll
        for (int off = 32; off; off >>= 1) {
            ssum += __shfl_xor(ssum, off);
#pragma unroll
            for (int h = 0; h < 8; ++h) o[h] += __shfl_xor(o[h], off);
        }

        if (lane == 0) {
            const float inv = 1.f/ssum;
            float f[8];
            float mu = 0.f;
#pragma unroll
            for (int h = 0; h < 8; ++h) { f[h] = o[h]*inv; mu += f[h]; }
            mu *= 0.125f;
            float var = 0.f;
#pragma unroll
            for (int h = 0; h < 8; ++h) { const float d = f[h]-mu; var += d*d; }
            var *= 0.125f;
            const float rinv = rsqrtf(var + 1e-5f);
            float on[8];
#pragma unroll
            for (int h = 0; h < 8; ++h)
                on[h] = (f[h]-mu)*rinv*ln_g[h] + ln_b[h];
            float sv[3];
#pragma unroll
            for (int c = 0; c < 3; ++c) {
                float z = bp[c];
#pragma unroll
                for (int j = 0; j < 8; ++j) z += on[j]*Wp[j*3 + c];
                const float sp = (z > 20.f) ? z : log1pf(__expf(z));
                sv[c] = fminf(sp, 6.0f) + 1e-6f;
                s_sig[w][c] = sv[c];        // sigmas never leave the block
            }
            atomicMax((int*)smax, __float_as_int(fmaxf(sv[0], sv[1])));
        }
    }
    gbar(ctl + 2*BAR_STRIDE);

    // ---------------- Phase 4: half + bilateral (tiles already in LDS) ----
    if (t == 0) {
        const int mi = __hip_atomic_load((const int*)smax, __ATOMIC_RELAXED,
                                         __HIP_MEMORY_SCOPE_AGENT);
        const float m = __int_as_float(mi);
        int h = (int)ceilf(m + 1.0f);
        if (h < 1) h = 1;
        if (h > 8) h = 8;                  // sigma cap 6 -> h <= 8 always
        s_half = h;
    }
    __syncthreads();
    const int half = s_half;
    const int k    = 2*half + 1;
    const int kk   = k*k;
    const int off0 = 8 - half;             // tile holds the half=8 window
    const int tx = t & 15, ty = t >> 4;

    // both spatial-weight tables, then a single sync; i-loop is sync-free
    for (int ii = t; ii < 2*kk; ii += 256) {
        const int i = (ii >= kk) ? 1 : 0;
        const int e = ii - (i ? kk : 0);
        const int dy = e / k, dx = e - dy*k;
        const float fy = (float)(dy - half), fx = (float)(dx - half);
        const float axc = -0.5f/(s_sig[i][0]*s_sig[i][0]);
        const float ayc = -0.5f/(s_sig[i][1]*s_sig[i][1]);
        spt[i][e] = __expf(ayc*fy*fy + axc*fx*fx);
    }
    __syncthreads();

#pragma unroll
    for (int i = 0; i < 2; ++i) {
        const int p  = blk*2 + i;
        const int b  = p / N_TOK, n = p % N_TOK;
        const int py = n / HP, px = n % HP;
        const float sr  = s_sig[i][2];
        const float ar2 = -0.72134752044448170f/(sr*sr); // -0.5*log2(e)/sr^2
        const float* tl = tile[i];
        const float c   = tl[(ty+8)*40 + (tx+8)];        // center, half-indep

        float num = 0.f, den = 0.f;
        for (int dy = 0; dy < k; ++dy) {
            const float* row = &tl[(ty+dy+off0)*40 + tx + off0];
            const float* spr = &spt[i][dy*k];  // lane-uniform -> broadcast
            for (int dx = 0; dx < k; ++dx) {
                const float pix = row[dx];
                const float d   = c - pix;
                const float wgt = spr[dx] * exp2f(ar2*d*d);
                den += wgt;
                num += wgt*pix;
            }
        }
        out[b*IMG*IMG + (py*PS + ty)*IMG + (px*PS + tx)] = num/(den + 1e-8f);
    }
}

// ---------------- launch: tiny ctl memset + ONE kernel ---------------------
extern "C" void kernel_launch(void* const* d_in, const int* in_sizes, int n_in,
                              void* d_out, int out_size, void* d_ws, size_t ws_size,
                              hipStream_t stream)
{
    const float* x    = (const float*)d_in[0];
    const float* Wq   = (const float*)d_in[1];
    const float* bq   = (const float*)d_in[2];
    const float* Wk   = (const float*)d_in[3];
    const float* bk   = (const float*)d_in[4];
    const float* Wv   = (const float*)d_in[5];
    const float* bv   = (const float*)d_in[6];
    const float* Wsq  = (const float*)d_in[7];
    const float* bsq  = (const float*)d_in[8];
    const float* Wsk  = (const float*)d_in[9];
    const float* bsk  = (const float*)d_in[10];
    const float* Wsv  = (const float*)d_in[11];
    const float* bsv  = (const float*)d_in[12];
    const float* ln_g = (const float*)d_in[13];
    const float* ln_b = (const float*)d_in[14];
    const float* Wp   = (const float*)d_in[15];
    const float* bp   = (const float*)d_in[16];

    float* W  = (float*)d_ws;
    float* k1 = W;            // 2*576*8 = 9216 floats each
    float* v1 = W +  9216;
    float* k2 = W + 18432;
    float* v2 = W + 27648;
    unsigned* ctl = (unsigned*)(W + 36864);   // 3*132 barrier words + smax

    hipMemsetAsync(ctl, 0, (3*BAR_STRIDE + 1)*sizeof(unsigned), stream);

    k_all<<<NBLK, 256, 0, stream>>>(x, Wq, bq, Wk, bk, Wv, bv,
                                    Wsq, bsq, Wsk, bsk, Wsv, bsv,
                                    ln_g, ln_b, Wp, bp,
                                    k1, v1, k2, v2, ctl, (float*)d_out);
}